// Round 10
// baseline (87.739 us; speedup 1.0000x reference)
//
#include <hip/hip_runtime.h>

// out[b,o,h,w] = sum_{c,k} (coef[k]/12.5) * rint( sum_j (12.5*w[k,c,o,j])*x_j + 12.5*b[k,c,o] )
// R10 = R9 (73.5us: packed-fp32, 1 o + 2 rows/wave, DPP neighbor exchange, XCD-keyed grid,
//           x ping-pong prefetch, [o][c][k][10] weight layout)
//  + block-wide ONE-TIME LDS staging of the o-slab weights (10 KB, 10 coalesced passes,
//    single barrier). Kills the per-c SGPR-chunked s_load/lgkmcnt stall (~5k cyc/c/wave).
//    Weights now flow LDS -> VGPR (ds_read_b128 broadcast, ~120cy, VGPR-budget prefetch).

typedef float v2f __attribute__((ext_vector_type(2)));

#define NB     8
#define NC     32
#define NO     32
#define NH     64
#define NW     64
#define NBATCH 8
#define FST    10                  // 9 taps + bias
#define PLANE  (NH * NW)
#define OSLAB  (NC * NB * FST)     // 2560 dwords = one o's full weight slab

// wq layout: [o:32][c:32][k:8][10]; value = 12.5*w, [9] = 12.5*bias
__global__ void prep_wq(const float* __restrict__ w, const float* __restrict__ bias,
                        float* __restrict__ wq) {
    int idx = blockIdx.x * 256 + threadIdx.x;      // (o*32+c)*8+k
    if (idx >= NC * NO * NB) return;
    int k = idx & 7;
    int c = (idx >> 3) & 31;
    int o = idx >> 8;
    int ch = c * NO + o;                           // channel in original [k][1024] layout
    const float* ws = w + ((size_t)k * (NC * NO) + ch) * 9;
    float* dst = wq + (size_t)idx * FST;
#pragma unroll
    for (int j = 0; j < 9; ++j) dst[j] = 12.5f * ws[j];
    dst[9] = 12.5f * bias[k * (NC * NO) + ch];
}

// lane w receives lane w-1's value; lane 0 -> 0 (bound_ctrl). (wave_shr:1 = 0x138)
__device__ __forceinline__ float dpp_left(float v) {
    return __builtin_bit_cast(float, __builtin_amdgcn_update_dpp(
        0, __builtin_bit_cast(int, v), 0x138, 0xf, 0xf, true));
}
// lane w receives lane w+1's value; lane 63 -> 0. (wave_shl:1 = 0x130)
__device__ __forceinline__ float dpp_right(float v) {
    return __builtin_bit_cast(float, __builtin_amdgcn_update_dpp(
        0, __builtin_bit_cast(int, v), 0x130, 0xf, 0xf, true));
}

// Wave = (b, o, row-pair h0,h0+1). lane = w. Block = 4 waves, same o, 8 rows.
// Grid (8 hb, 32 o, 8 b): dispatch id % 8 == hb -> one x slab per XCD L2.
__global__ __launch_bounds__(256, 8) void demolition_conv(
        const float* __restrict__ x, const float* __restrict__ wq,
        float* __restrict__ out) {
    __shared__ float wl[OSLAB];                    // [c:32][k:8][10] for this block's o

    const int tid  = threadIdx.x;
    const int w    = tid & 63;
    const int wave = tid >> 6;
    const int hb   = blockIdx.x;                   // 0..7 (XCD key)
    const int o    = blockIdx.y;                   // 0..31
    const int b    = blockIdx.z;
    const int h0   = hb * 8 + wave * 2;            // 0..62 even

    // one-time cooperative stage of the 10 KB o-slab (2560 = 10 x 256, coalesced)
    const float* wsrc = wq + (size_t)o * OSLAB;
#pragma unroll
    for (int i = 0; i < OSLAB / 256; ++i)
        wl[i * 256 + tid] = wsrc[i * 256 + tid];
    __syncthreads();

    const float ckq[8] = {
        -128.f / 127.f / 12.5f,  1.f / 127.f / 12.5f,  2.f / 127.f / 12.5f,
           4.f / 127.f / 12.5f,  8.f / 127.f / 12.5f, 16.f / 127.f / 12.5f,
          32.f / 127.f / 12.5f, 64.f / 127.f / 12.5f };

    v2f acc = {0.f, 0.f};

    const bool top = (h0 > 0), bot = (h0 < NH - 2);
    const int  rT  = top ? -NW : 0;        // clamped address for row h0-1
    const int  rB  = bot ? 2 * NW : NW;    // clamped address for row h0+2

    const float* xc = x + ((size_t)b * NC * NH + h0) * NW + w;

    // one channel-step: DPP exchange + pack + 8 filters from LDS. FMA order == R9 (canary).
    auto step = [&](float xm1, float x0, float x1, float x2, int c) {
        if (!top) xm1 = 0.f;                       // wave-uniform
        if (!bot) x2  = 0.f;

        float lm1 = dpp_left(xm1), l0 = dpp_left(x0), l1 = dpp_left(x1), l2 = dpp_left(x2);
        float rm1 = dpp_right(xm1), r0 = dpp_right(x0), r1 = dpp_right(x1), r2 = dpp_right(x2);

        v2f t[9];
        t[0].x = lm1; t[0].y = l0;
        t[1].x = xm1; t[1].y = x0;
        t[2].x = rm1; t[2].y = r0;
        t[3].x = l0;  t[3].y = l1;
        t[4].x = x0;  t[4].y = x1;
        t[5].x = r0;  t[5].y = r1;
        t[6].x = l1;  t[6].y = l2;
        t[7].x = x1;  t[7].y = x2;
        t[8].x = r1;  t[8].y = r2;

        const float* wp = &wl[c * (NB * FST)];
#pragma unroll
        for (int k = 0; k < NB; ++k) {
            const float* f = wp + k * FST;         // compile-time imm offsets -> ds_read_b128
            v2f s; s.x = f[9]; s.y = f[9];         // pre-scaled bias (both rows)
#pragma unroll
            for (int j = 0; j < 9; ++j) {
                v2f wv; wv.x = f[j]; wv.y = f[j];  // uniform splat (LDS broadcast)
                s = __builtin_elementwise_fma(wv, t[j], s);
            }
            v2f rr; rr.x = rintf(s.x); rr.y = rintf(s.y);
            v2f cv; cv.x = ckq[k]; cv.y = ckq[k];
            acc = __builtin_elementwise_fma(cv, rr, acc);
        }
    };

    // prologue: raw loads for c=0 (ping)
    float am1 = xc[rT], a0 = xc[0], a1 = xc[NW], a2 = xc[rB];

#pragma unroll 1
    for (int c = 0; c < NC; c += 2) {
        // prefetch c+1 (pong) — issued BEFORE compute of c
        const float* xn = xc + PLANE;
        float bm1 = xn[rT], b0 = xn[0], b1 = xn[NW], b2 = xn[rB];
        step(am1, a0, a1, a2, c);

        // prefetch c+2 (ping); clamp at tail (wave-uniform, loads harmless & unused)
        const float* xm = (c + 2 < NC) ? xn + PLANE : xn;
        am1 = xm[rT]; a0 = xm[0]; a1 = xm[NW]; a2 = xm[rB];
        step(bm1, b0, b1, b2, c + 1);

        xc = xm;
    }

    float* op = out + (((size_t)b * NO + o) * NH + h0) * NW + w;
    op[0]  = acc.x;
    op[NW] = acc.y;
}

extern "C" void kernel_launch(void* const* d_in, const int* in_sizes, int n_in,
                              void* d_out, int out_size, void* d_ws, size_t ws_size,
                              hipStream_t stream) {
    const float* x    = (const float*)d_in[0];   // [8,32,64,64]
    const float* wt   = (const float*)d_in[1];   // [8,1024,1,3,3]
    const float* bias = (const float*)d_in[2];   // [8,1024]
    float* out = (float*)d_out;                  // [8,32,64,64]
    float* wq  = (float*)d_ws;                   // 8192*10 floats = 320 KiB

    prep_wq<<<(NC * NO * NB + 255) / 256, 256, 0, stream>>>(wt, bias, wq);

    dim3 grid(8, NO, NBATCH);                    // (hb, o, b): id % 8 == hb (XCD key)
    demolition_conv<<<grid, 256, 0, stream>>>(x, wq, out);
}

// Round 11
// 70.751 us; speedup vs baseline: 1.2401x; 1.2401x over previous
//
#include <hip/hip_runtime.h>

// out[b,o,h,w] = sum_{c,k} (coef[k]/12.5) * rint( sum_j (12.5*w[k,c,o,j])*x_j + 12.5*b[k,c,o] )
// R11 = R9 body (73.5us: packed-fp32, 1 o + 2 rows/wave, DPP neighbor exchange, XCD-keyed
//       grid, x ping-pong prefetch, [o][c][k][10] contiguous weights)
//  + c-range split across 2 waves (c 0..15 / 16..31), combined post-rint via 2KB LDS.
//    16384 waves -> 32 resident/CU at TWO c-phases: decorrelates the per-c weight-s_load
//    waitcnt windows that left ~21us of VALU idle (VALUBusy 71% @ 73.5us).

typedef float v2f __attribute__((ext_vector_type(2)));

#define NB     8
#define NC     32
#define NO     32
#define NH     64
#define NW     64
#define NBATCH 8
#define FST    10                  // 9 taps + bias
#define PLANE  (NH * NW)
#define WCSTEP (NB * FST)          // dwords per c step in wq (contiguous per-o stream)
#define CHALF  16                  // channels per wave

// wq layout: [o:32][c:32][k:8][10]; value = 12.5*w, [9] = 12.5*bias
__global__ void prep_wq(const float* __restrict__ w, const float* __restrict__ bias,
                        float* __restrict__ wq) {
    int idx = blockIdx.x * 256 + threadIdx.x;      // (o*32+c)*8+k
    if (idx >= NC * NO * NB) return;
    int k = idx & 7;
    int c = (idx >> 3) & 31;
    int o = idx >> 8;
    int ch = c * NO + o;                           // channel in original [k][1024] layout
    const float* ws = w + ((size_t)k * (NC * NO) + ch) * 9;
    float* dst = wq + (size_t)idx * FST;
#pragma unroll
    for (int j = 0; j < 9; ++j) dst[j] = 12.5f * ws[j];
    dst[9] = 12.5f * bias[k * (NC * NO) + ch];
}

// lane w receives lane w-1's value; lane 0 -> 0 (bound_ctrl). (wave_shr:1 = 0x138)
__device__ __forceinline__ float dpp_left(float v) {
    return __builtin_bit_cast(float, __builtin_amdgcn_update_dpp(
        0, __builtin_bit_cast(int, v), 0x138, 0xf, 0xf, true));
}
// lane w receives lane w+1's value; lane 63 -> 0. (wave_shl:1 = 0x130)
__device__ __forceinline__ float dpp_right(float v) {
    return __builtin_bit_cast(float, __builtin_amdgcn_update_dpp(
        0, __builtin_bit_cast(int, v), 0x130, 0xf, 0xf, true));
}

// One channel-step: DPP neighbor exchange + pack + 8 filters. FMA order == R8/R9 (canary).
__device__ __forceinline__ v2f step(float xm1, float x0, float x1, float x2,
                                    bool top, bool bot,
                                    const float* __restrict__ wp, v2f acc,
                                    const float* __restrict__ ckq) {
    if (!top) xm1 = 0.f;                           // wave-uniform
    if (!bot) x2  = 0.f;

    float lm1 = dpp_left(xm1), l0 = dpp_left(x0), l1 = dpp_left(x1), l2 = dpp_left(x2);
    float rm1 = dpp_right(xm1), r0 = dpp_right(x0), r1 = dpp_right(x1), r2 = dpp_right(x2);

    v2f t[9];
    t[0].x = lm1; t[0].y = l0;
    t[1].x = xm1; t[1].y = x0;
    t[2].x = rm1; t[2].y = r0;
    t[3].x = l0;  t[3].y = l1;
    t[4].x = x0;  t[4].y = x1;
    t[5].x = r0;  t[5].y = r1;
    t[6].x = l1;  t[6].y = l2;
    t[7].x = x1;  t[7].y = x2;
    t[8].x = r1;  t[8].y = r2;

#pragma unroll
    for (int k = 0; k < NB; ++k) {
        const float* f = wp + k * FST;             // compile-time imm offsets off scalar base
        v2f s; s.x = f[9]; s.y = f[9];             // pre-scaled bias (both rows)
#pragma unroll
        for (int j = 0; j < 9; ++j) {
            v2f wv; wv.x = f[j]; wv.y = f[j];      // uniform splat
            s = __builtin_elementwise_fma(wv, t[j], s);
        }
        v2f rr; rr.x = rintf(s.x); rr.y = rintf(s.y);
        v2f cv; cv.x = ckq[k]; cv.y = ckq[k];
        acc = __builtin_elementwise_fma(cv, rr, acc);
    }
    return acc;
}

// Block = 8 waves (512 thr) = 4 row-pairs x 2 c-halves, one o, 8 rows.
// Grid (8 hb, 32 o, 8 b): dispatch id % 8 == hb (XCD key); co-resident blocks share o (K$).
__global__ __launch_bounds__(512, 8) void demolition_conv(
        const float* __restrict__ x, const float* __restrict__ wq,
        float* __restrict__ out) {
    __shared__ float part[4][2][64];               // [hsub][row01][w], written by chalf=1

    const int tid   = threadIdx.x;
    const int w     = tid & 63;
    const int wave  = tid >> 6;                    // 0..7
    const int chalf = wave & 1;                    // c-half this wave reduces
    const int hsub  = wave >> 1;                   // 0..3 (row-pair within 8-row slab)
    const int hb    = blockIdx.x;                  // 0..7 (XCD key)
    const int o     = blockIdx.y;                  // 0..31
    const int b     = blockIdx.z;
    const int h0    = hb * 8 + hsub * 2;           // 0..62 even

    const float ckq[8] = {
        -128.f / 127.f / 12.5f,  1.f / 127.f / 12.5f,  2.f / 127.f / 12.5f,
           4.f / 127.f / 12.5f,  8.f / 127.f / 12.5f, 16.f / 127.f / 12.5f,
          32.f / 127.f / 12.5f, 64.f / 127.f / 12.5f };

    v2f acc = {0.f, 0.f};

    const bool top = (h0 > 0), bot = (h0 < NH - 2);   // wave-uniform
    const int  rT  = top ? -NW : 0;        // clamped address for row h0-1
    const int  rB  = bot ? 2 * NW : NW;    // clamped address for row h0+2

    const float* xc = x + (((size_t)b * NC + chalf * CHALF) * NH + h0) * NW + w;
    const float* wp = wq + __builtin_amdgcn_readfirstlane(
                          o * (NC * NB * FST) + chalf * CHALF * WCSTEP);

    // prologue: raw loads for first channel (ping)
    float am1 = xc[rT], a0 = xc[0], a1 = xc[NW], a2 = xc[rB];

#pragma unroll 1
    for (int c = 0; c < CHALF; c += 2) {
        // prefetch c+1 (pong) — issued BEFORE compute of c
        const float* xn = xc + PLANE;
        float bm1 = xn[rT], b0 = xn[0], b1 = xn[NW], b2 = xn[rB];
        acc = step(am1, a0, a1, a2, top, bot, wp, acc, ckq);
        wp += WCSTEP;

        // prefetch c+2 (ping); clamp at tail (wave-uniform, loads harmless & unused)
        const float* xm = (c + 2 < CHALF) ? xn + PLANE : xn;
        am1 = xm[rT]; a0 = xm[0]; a1 = xm[NW]; a2 = xm[rB];
        acc = step(bm1, b0, b1, b2, top, bot, wp, acc, ckq);
        wp += WCSTEP;

        xc = xm;
    }

    // combine the two c-halves (post-rint partial sums; exact bins, assoc-only change)
    if (chalf) {
        part[hsub][0][w] = acc.x;
        part[hsub][1][w] = acc.y;
    }
    __syncthreads();
    if (!chalf) {
        float* op = out + (((size_t)b * NO + o) * NH + h0) * NW + w;
        op[0]  = acc.x + part[hsub][0][w];
        op[NW] = acc.y + part[hsub][1][w];
    }
}

extern "C" void kernel_launch(void* const* d_in, const int* in_sizes, int n_in,
                              void* d_out, int out_size, void* d_ws, size_t ws_size,
                              hipStream_t stream) {
    const float* x    = (const float*)d_in[0];   // [8,32,64,64]
    const float* wt   = (const float*)d_in[1];   // [8,1024,1,3,3]
    const float* bias = (const float*)d_in[2];   // [8,1024]
    float* out = (float*)d_out;                  // [8,32,64,64]
    float* wq  = (float*)d_ws;                   // 8192*10 floats = 320 KiB

    prep_wq<<<(NC * NO * NB + 255) / 256, 256, 0, stream>>>(wt, bias, wq);

    dim3 grid(8, NO, NBATCH);                    // (hb, o, b): id % 8 == hb (XCD key)
    demolition_conv<<<grid, 512, 0, stream>>>(x, wq, out);
}

// Round 12
// 70.520 us; speedup vs baseline: 1.2442x; 1.0033x over previous
//
#include <hip/hip_runtime.h>

// out[b,o,h,w] = sum_{c,k} (coef[k]/12.5) * rint( sum_j (12.5*w[k,c,o,j])*x_j + 12.5*b[k,c,o] )
// R12 = R11 body (70.75us), scheduling-only change:
//   4-way c-split (8 ch/wave, 4 phases), 256-thr blocks = 4 waves = one (b,o,row-pair),
//   32768 waves / 8192 blocks -> 8 co-resident blocks/CU in 4 rounds (finer drain),
//   LDS tree combine (post-rint, outer-sum reassociation only). XCD-keyed grid kept.

typedef float v2f __attribute__((ext_vector_type(2)));

#define NB     8
#define NC     32
#define NO     32
#define NH     64
#define NW     64
#define NBATCH 8
#define FST    10                  // 9 taps + bias
#define PLANE  (NH * NW)
#define WCSTEP (NB * FST)          // dwords per c step in wq (contiguous per-o stream)
#define CQUART 8                   // channels per wave

// wq layout: [o:32][c:32][k:8][10]; value = 12.5*w, [9] = 12.5*bias
__global__ void prep_wq(const float* __restrict__ w, const float* __restrict__ bias,
                        float* __restrict__ wq) {
    int idx = blockIdx.x * 256 + threadIdx.x;      // (o*32+c)*8+k
    if (idx >= NC * NO * NB) return;
    int k = idx & 7;
    int c = (idx >> 3) & 31;
    int o = idx >> 8;
    int ch = c * NO + o;                           // channel in original [k][1024] layout
    const float* ws = w + ((size_t)k * (NC * NO) + ch) * 9;
    float* dst = wq + (size_t)idx * FST;
#pragma unroll
    for (int j = 0; j < 9; ++j) dst[j] = 12.5f * ws[j];
    dst[9] = 12.5f * bias[k * (NC * NO) + ch];
}

// lane w receives lane w-1's value; lane 0 -> 0 (bound_ctrl). (wave_shr:1 = 0x138)
__device__ __forceinline__ float dpp_left(float v) {
    return __builtin_bit_cast(float, __builtin_amdgcn_update_dpp(
        0, __builtin_bit_cast(int, v), 0x138, 0xf, 0xf, true));
}
// lane w receives lane w+1's value; lane 63 -> 0. (wave_shl:1 = 0x130)
__device__ __forceinline__ float dpp_right(float v) {
    return __builtin_bit_cast(float, __builtin_amdgcn_update_dpp(
        0, __builtin_bit_cast(int, v), 0x130, 0xf, 0xf, true));
}

// One channel-step: DPP neighbor exchange + pack + 8 filters. FMA order == R8..R11 (canary).
__device__ __forceinline__ v2f step(float xm1, float x0, float x1, float x2,
                                    bool top, bool bot,
                                    const float* __restrict__ wp, v2f acc,
                                    const float* __restrict__ ckq) {
    if (!top) xm1 = 0.f;                           // wave-uniform
    if (!bot) x2  = 0.f;

    float lm1 = dpp_left(xm1), l0 = dpp_left(x0), l1 = dpp_left(x1), l2 = dpp_left(x2);
    float rm1 = dpp_right(xm1), r0 = dpp_right(x0), r1 = dpp_right(x1), r2 = dpp_right(x2);

    v2f t[9];
    t[0].x = lm1; t[0].y = l0;
    t[1].x = xm1; t[1].y = x0;
    t[2].x = rm1; t[2].y = r0;
    t[3].x = l0;  t[3].y = l1;
    t[4].x = x0;  t[4].y = x1;
    t[5].x = r0;  t[5].y = r1;
    t[6].x = l1;  t[6].y = l2;
    t[7].x = x1;  t[7].y = x2;
    t[8].x = r1;  t[8].y = r2;

#pragma unroll
    for (int k = 0; k < NB; ++k) {
        const float* f = wp + k * FST;             // compile-time imm offsets off scalar base
        v2f s; s.x = f[9]; s.y = f[9];             // pre-scaled bias (both rows)
#pragma unroll
        for (int j = 0; j < 9; ++j) {
            v2f wv; wv.x = f[j]; wv.y = f[j];      // uniform splat
            s = __builtin_elementwise_fma(wv, t[j], s);
        }
        v2f rr; rr.x = rintf(s.x); rr.y = rintf(s.y);
        v2f cv; cv.x = ckq[k]; cv.y = ckq[k];
        acc = __builtin_elementwise_fma(cv, rr, acc);
    }
    return acc;
}

// Block = 4 waves (256 thr) = one (b, o, row-pair) x 4 c-quarters.
// Grid (8 hb, o*4+hsub, b): dispatch id % 8 == hb (XCD key); same-o blocks burst per XCD.
__global__ __launch_bounds__(256, 8) void demolition_conv(
        const float* __restrict__ x, const float* __restrict__ wq,
        float* __restrict__ out) {
    __shared__ float part[3][2][64];               // written by cq=1..3

    const int tid  = threadIdx.x;
    const int w    = tid & 63;
    const int cq   = tid >> 6;                     // 0..3 (c-quarter)
    const int hb   = blockIdx.x;                   // 0..7 (XCD key)
    const int o    = blockIdx.y >> 2;              // 0..31
    const int hsub = blockIdx.y & 3;               // 0..3
    const int b    = blockIdx.z;
    const int h0   = hb * 8 + hsub * 2;            // 0..62 even

    const float ckq[8] = {
        -128.f / 127.f / 12.5f,  1.f / 127.f / 12.5f,  2.f / 127.f / 12.5f,
           4.f / 127.f / 12.5f,  8.f / 127.f / 12.5f, 16.f / 127.f / 12.5f,
          32.f / 127.f / 12.5f, 64.f / 127.f / 12.5f };

    v2f acc = {0.f, 0.f};

    const bool top = (h0 > 0), bot = (h0 < NH - 2);   // wave-uniform
    const int  rT  = top ? -NW : 0;        // clamped address for row h0-1
    const int  rB  = bot ? 2 * NW : NW;    // clamped address for row h0+2

    const float* xc = x + (((size_t)b * NC + cq * CQUART) * NH + h0) * NW + w;
    const float* wp = wq + __builtin_amdgcn_readfirstlane(
                          o * (NC * NB * FST) + cq * CQUART * WCSTEP);

    // prologue: raw loads for first channel (ping)
    float am1 = xc[rT], a0 = xc[0], a1 = xc[NW], a2 = xc[rB];

#pragma unroll 1
    for (int c = 0; c < CQUART; c += 2) {
        // prefetch c+1 (pong) — issued BEFORE compute of c
        const float* xn = xc + PLANE;
        float bm1 = xn[rT], b0 = xn[0], b1 = xn[NW], b2 = xn[rB];
        acc = step(am1, a0, a1, a2, top, bot, wp, acc, ckq);
        wp += WCSTEP;

        // prefetch c+2 (ping); clamp at tail (wave-uniform, loads harmless & unused)
        const float* xm = (c + 2 < CQUART) ? xn + PLANE : xn;
        am1 = xm[rT]; a0 = xm[0]; a1 = xm[NW]; a2 = xm[rB];
        acc = step(bm1, b0, b1, b2, top, bot, wp, acc, ckq);
        wp += WCSTEP;

        xc = xm;
    }

    // combine the four c-quarters (post-rint partials; outer-sum reassociation only)
    if (cq) {
        part[cq - 1][0][w] = acc.x;
        part[cq - 1][1][w] = acc.y;
    }
    __syncthreads();
    if (!cq) {
        float* op = out + (((size_t)b * NO + o) * NH + h0) * NW + w;
        op[0]  = acc.x + part[0][0][w] + part[1][0][w] + part[2][0][w];
        op[NW] = acc.y + part[0][1][w] + part[1][1][w] + part[2][1][w];
    }
}

extern "C" void kernel_launch(void* const* d_in, const int* in_sizes, int n_in,
                              void* d_out, int out_size, void* d_ws, size_t ws_size,
                              hipStream_t stream) {
    const float* x    = (const float*)d_in[0];   // [8,32,64,64]
    const float* wt   = (const float*)d_in[1];   // [8,1024,1,3,3]
    const float* bias = (const float*)d_in[2];   // [8,1024]
    float* out = (float*)d_out;                  // [8,32,64,64]
    float* wq  = (float*)d_ws;                   // 8192*10 floats = 320 KiB

    prep_wq<<<(NC * NO * NB + 255) / 256, 256, 0, stream>>>(wt, bias, wq);

    dim3 grid(8, NO * 4, NBATCH);                // (hb, o*4+hsub, b): id % 8 == hb (XCD key)
    demolition_conv<<<grid, 256, 0, stream>>>(x, wq, out);
}